// Round 12
// baseline (260.698 us; speedup 1.0000x reference)
//
#include <hip/hip_runtime.h>
#include <hip/hip_bf16.h>

#define D 128
#define CHUNK 8192     // edges per build block
#define SPAN_CAP 768   // LDS col-stage capacity (8-node span ~ Poisson(264), sigma~16)

// NOTE: build path packs (dst&255, src) into one uint -> requires N <= 65536.

typedef __attribute__((ext_vector_type(8))) short short8;
typedef __attribute__((ext_vector_type(4))) float floatx4;

// fp32 -> bf16 round-to-nearest-even (bit pattern)
static __device__ inline unsigned int f2bf(float f) {
    unsigned int u = __float_as_uint(f);
    return (u + 0x7FFFu + ((u >> 16) & 1u)) >> 16;
}
static __device__ inline float bflo(unsigned int u) { return __uint_as_float(u << 16); }
static __device__ inline float bfhi(unsigned int u) { return __uint_as_float(u & 0xFFFF0000u); }

// ---------------------------------------------------------------- K0+K1 fused:
// blocks [0,16): swizzle W0/W1 into MFMA B-fragment order (hi/lo bf16 split)
// blocks [16,16+NB): per-chunk dst-bucket histogram
__global__ __launch_bounds__(256) void k01_swz_hist(const float* __restrict__ W0,
                                                    const float* __restrict__ W1,
                                                    short8* __restrict__ whi0, short8* __restrict__ wlo0,
                                                    short8* __restrict__ whi1, short8* __restrict__ wlo1,
                                                    const int* __restrict__ dst,
                                                    int* __restrict__ blockhist, int E_) {
    __shared__ int h[256];
    const int tid = threadIdx.x;
    if (blockIdx.x < 16) {
        int gid = blockIdx.x * 256 + tid; // 0..4095
        const float* W = (gid < 2048) ? W0 : W1;
        short8* whi = (gid < 2048) ? whi0 : whi1;
        short8* wlo = (gid < 2048) ? wlo0 : wlo1;
        int t2 = gid & 2047;
        int t = t2 >> 8, q = (t2 >> 6) & 3, lane = t2 & 63;
        short8 hi, lo;
        #pragma unroll
        for (int j = 0; j < 8; ++j) {
            int k = q * 32 + (lane >> 4) * 8 + j;
            int n = t * 16 + (lane & 15);
            float w = W[k * D + n];
            unsigned int hh = f2bf(w);
            hi[j] = (short)hh;
            lo[j] = (short)f2bf(w - __uint_as_float(hh << 16));
        }
        whi[t2] = hi;
        wlo[t2] = lo;
    } else {
        const int b = blockIdx.x - 16;
        h[tid] = 0;
        __syncthreads();
        const int e0 = b * CHUNK;
        const int e1 = min(E_, e0 + CHUNK);
        for (int e = e0 + tid; e < e1; e += 256)
            atomicAdd(&h[dst[e] >> 8], 1);
        __syncthreads();
        blockhist[b * 256 + tid] = h[tid];
    }
}

// ---------------------------------------------------------------- K2+K3 fused: redundant scan + scatter
__global__ __launch_bounds__(256) void k23_scan_scatter(const int* __restrict__ blockhist,
                                                        const int* __restrict__ dst,
                                                        const int* __restrict__ src,
                                                        int* __restrict__ bucket_offs,
                                                        unsigned int* __restrict__ buf,
                                                        int NB, int NBUK, int E_) {
    __shared__ int s[256];
    __shared__ int c[256];
    const int myb = blockIdx.x, tid = threadIdx.x;
    int total = 0, prefix = 0;
    #pragma unroll 4
    for (int b2 = 0; b2 < NB; ++b2) {
        int t = blockhist[b2 * 256 + tid];
        total += t;
        prefix += (b2 < myb) ? t : 0;
    }
    s[tid] = total;
    __syncthreads();
    #pragma unroll
    for (int off = 1; off < 256; off <<= 1) {
        int x = (tid >= off) ? s[tid - off] : 0;
        __syncthreads();
        s[tid] += x;
        __syncthreads();
    }
    int bstart = s[tid] - total; // exclusive bucket start
    if (myb == 0) {
        if (tid < NBUK) bucket_offs[tid] = bstart;
        if (tid == 0) bucket_offs[NBUK] = E_;
    }
    c[tid] = bstart + prefix;
    __syncthreads();

    const int e0 = myb * CHUNK;
    const int e1 = min(E_, e0 + CHUNK);
    for (int e = e0 + tid; e < e1; e += 256) {
        int v = dst[e];
        int sdx = src[e];
        int pos = atomicAdd(&c[v >> 8], 1);
        buf[pos] = (unsigned int)sdx | ((unsigned int)(v & 255) << 16);
    }
}

// ---------------------------------------------------------------- K4: per-bucket counting sort (by dst&255) -> col, offs, dinv
__global__ __launch_bounds__(256) void k4_bucket(const unsigned int* __restrict__ buf,
                                                 const int* __restrict__ bucket_offs,
                                                 int* __restrict__ offs,
                                                 float* __restrict__ dinv,
                                                 int* __restrict__ col, int N_, int E_) {
    __shared__ int h[256];
    __shared__ int s[256];
    __shared__ int c[256];
    const int beta = blockIdx.x, tid = threadIdx.x;
    const int start = bucket_offs[beta];
    const int end   = bucket_offs[beta + 1];

    h[tid] = 0;
    __syncthreads();
    for (int e = start + tid; e < end; e += 256)
        atomicAdd(&h[(buf[e] >> 16) & 255], 1);
    __syncthreads();

    int deg = h[tid];
    s[tid] = deg;
    __syncthreads();
    #pragma unroll
    for (int off = 1; off < 256; off <<= 1) {
        int x = (tid >= off) ? s[tid - off] : 0;
        __syncthreads();
        s[tid] += x;
        __syncthreads();
    }
    int excl = s[tid] - deg;

    int v0 = beta * 256 + tid;
    if (v0 < N_) {
        offs[v0] = start + excl;
        dinv[v0] = rsqrtf((float)(deg + 1));
    }
    if (beta == 0 && tid == 0) offs[N_] = E_;
    c[tid] = start + excl;
    __syncthreads();

    for (int e = start + tid; e < end; e += 256) {
        unsigned int p = buf[e];
        int pos = atomicAdd(&c[(p >> 16) & 255], 1);
        col[pos] = (int)(p & 0xFFFFu);
    }
}

// ---------------------------------------------------------------- MFMA GEMM: G(bf16, 2 col-planes) = (A @ W) * dinv[row]
__global__ __launch_bounds__(256) void gemm_mfma(const float* __restrict__ A,
                                                 const short8* __restrict__ whi,
                                                 const short8* __restrict__ wlo,
                                                 const float* __restrict__ dinv,
                                                 unsigned int* __restrict__ Gu, int nrows) {
    __shared__ float tileT[128][65];

    const int tid  = threadIdx.x;
    const int wave = tid >> 6, lane = tid & 63;
    const int m = lane & 15, quad = lane >> 4;
    const int rowInBlk = wave * 16;
    const int arow = min(blockIdx.x * 64 + rowInBlk + m, nrows - 1);
    const float* Ap = A + (size_t)arow * D + quad * 8;

    floatx4 acc[8];
    #pragma unroll
    for (int t = 0; t < 8; ++t) acc[t] = (floatx4){0.f, 0.f, 0.f, 0.f};

    #pragma unroll
    for (int q = 0; q < 4; ++q) {
        float4 a0 = *(const float4*)(Ap + q * 32);
        float4 a1 = *(const float4*)(Ap + q * 32 + 4);
        float av[8] = {a0.x, a0.y, a0.z, a0.w, a1.x, a1.y, a1.z, a1.w};
        short8 ahi, alo;
        #pragma unroll
        for (int j = 0; j < 8; ++j) {
            unsigned int h = f2bf(av[j]);
            ahi[j] = (short)h;
            alo[j] = (short)f2bf(av[j] - __uint_as_float(h << 16));
        }
        #pragma unroll
        for (int t = 0; t < 8; ++t) {
            short8 bh = whi[(t * 4 + q) * 64 + lane];
            short8 bl = wlo[(t * 4 + q) * 64 + lane];
            acc[t] = __builtin_amdgcn_mfma_f32_16x16x32_bf16(ahi, bh, acc[t], 0, 0, 0);
            acc[t] = __builtin_amdgcn_mfma_f32_16x16x32_bf16(alo, bh, acc[t], 0, 0, 0);
            acc[t] = __builtin_amdgcn_mfma_f32_16x16x32_bf16(ahi, bl, acc[t], 0, 0, 0);
        }
    }

    #pragma unroll
    for (int t = 0; t < 8; ++t)
        #pragma unroll
        for (int r = 0; r < 4; ++r)
            tileT[t * 16 + m][rowInBlk + quad * 4 + r] = acc[t][r];
    __syncthreads();

    const int orow = tid >> 2, seg = tid & 3;     // seg -> cols [seg*32, seg*32+32)
    const int grow = blockIdx.x * 64 + orow;
    if (grow < nrows) {
        float s = dinv[grow];
        const int p = seg >> 1;                   // plane
        unsigned int* Gp = Gu + ((size_t)(p * nrows + grow)) * 32 + (seg & 1) * 16;
        #pragma unroll
        for (int i = 0; i < 4; ++i) {
            int c0 = seg * 32 + i * 8;
            uint4 o4;
            o4.x = f2bf(tileT[c0 + 0][orow] * s) | (f2bf(tileT[c0 + 1][orow] * s) << 16);
            o4.y = f2bf(tileT[c0 + 2][orow] * s) | (f2bf(tileT[c0 + 3][orow] * s) << 16);
            o4.z = f2bf(tileT[c0 + 4][orow] * s) | (f2bf(tileT[c0 + 5][orow] * s) << 16);
            o4.w = f2bf(tileT[c0 + 6][orow] * s) | (f2bf(tileT[c0 + 7][orow] * s) << 16);
            ((uint4*)Gp)[i] = o4;
        }
    }
}

// ---------------------------------------------------------------- out[i] = relu(dinv[i]*(sum_j g[j] + g[i]) + b)
// R11 structure + depth-2 software pipeline: batch b+1's LDS col reads and 8
// gathers are in flight while batch b accumulates -> per-node latency windows
// roughly halve. Tail = one clamped, lane-masked batch (16 cndmask/node).
__global__ __launch_bounds__(256) void aggregate_kernel(const unsigned int* __restrict__ Gu,
                                                        const int* __restrict__ offs,
                                                        const int* __restrict__ col,
                                                        const float* __restrict__ dinv,
                                                        const float* __restrict__ bias,
                                                        float* __restrict__ out, int nnodes,
                                                        int ngroups) {
    __shared__ int scol[SPAN_CAP];
    __shared__ int soffs[9];
    const int bid   = blockIdx.x;
    const int xcd   = bid & 7;
    const int plane = xcd >> 2;
    const int i     = (bid >> 3) * 4 + (xcd & 3);
    if (i >= ngroups) return;
    const int tid   = threadIdx.x;
    const int node0 = i * 8;

    if (tid < 9) soffs[tid] = offs[min(node0 + tid, nnodes)];
    __syncthreads();
    const int s0   = soffs[0];
    const int span = soffs[8] - s0;
    const bool lds_ok = (span <= SPAN_CAP);
    if (lds_ok) {
        for (int k = tid; k < span; k += 256) scol[k] = col[s0 + k];
    }
    __syncthreads();

    const int lane = tid & 31;
    const int node = node0 + (tid >> 5);
    if (node >= nnodes) return;
    const unsigned int* P = Gu + (size_t)plane * nnodes * 32;

    unsigned int su = P[(size_t)node * 32 + lane]; // self-loop
    float ax = bflo(su), ay = bfhi(su);

    const int s = soffs[tid >> 5];
    const int e = soffs[(tid >> 5) + 1];
    const int deg = e - s;

    if (lds_ok) {
        const int b0 = s - s0;
        const int nb8 = deg >> 3;
        unsigned int a0, a1, a2, a3, a4, a5, a6, a7;
        unsigned int q0, q1, q2, q3, q4, q5, q6, q7;
        if (nb8 > 0) {
            int j0 = scol[b0 + 0], j1 = scol[b0 + 1], j2 = scol[b0 + 2], j3 = scol[b0 + 3];
            int j4 = scol[b0 + 4], j5 = scol[b0 + 5], j6 = scol[b0 + 6], j7 = scol[b0 + 7];
            a0 = P[(size_t)j0 * 32 + lane]; a1 = P[(size_t)j1 * 32 + lane];
            a2 = P[(size_t)j2 * 32 + lane]; a3 = P[(size_t)j3 * 32 + lane];
            a4 = P[(size_t)j4 * 32 + lane]; a5 = P[(size_t)j5 * 32 + lane];
            a6 = P[(size_t)j6 * 32 + lane]; a7 = P[(size_t)j7 * 32 + lane];
        }
        for (int b = 0; b < nb8; ++b) {
            const bool more = (b + 1 < nb8);
            if (more) {
                const int bb = b0 + (b + 1) * 8;
                int j0 = scol[bb + 0], j1 = scol[bb + 1], j2 = scol[bb + 2], j3 = scol[bb + 3];
                int j4 = scol[bb + 4], j5 = scol[bb + 5], j6 = scol[bb + 6], j7 = scol[bb + 7];
                q0 = P[(size_t)j0 * 32 + lane]; q1 = P[(size_t)j1 * 32 + lane];
                q2 = P[(size_t)j2 * 32 + lane]; q3 = P[(size_t)j3 * 32 + lane];
                q4 = P[(size_t)j4 * 32 + lane]; q5 = P[(size_t)j5 * 32 + lane];
                q6 = P[(size_t)j6 * 32 + lane]; q7 = P[(size_t)j7 * 32 + lane];
            }
            ax += ((bflo(a0) + bflo(a1)) + (bflo(a2) + bflo(a3))) +
                  ((bflo(a4) + bflo(a5)) + (bflo(a6) + bflo(a7)));
            ay += ((bfhi(a0) + bfhi(a1)) + (bfhi(a2) + bfhi(a3))) +
                  ((bfhi(a4) + bfhi(a5)) + (bfhi(a6) + bfhi(a7)));
            if (more) {
                a0 = q0; a1 = q1; a2 = q2; a3 = q3;
                a4 = q4; a5 = q5; a6 = q6; a7 = q7;
            }
        }
        const int rem = deg & 7;
        if (rem) {
            const int kk = b0 + nb8 * 8;
            const int last = b0 + deg - 1;
            int j0 = scol[kk];
            int j1 = scol[min(kk + 1, last)], j2 = scol[min(kk + 2, last)];
            int j3 = scol[min(kk + 3, last)], j4 = scol[min(kk + 4, last)];
            int j5 = scol[min(kk + 5, last)], j6 = scol[min(kk + 6, last)];
            int j7 = scol[min(kk + 7, last)];
            unsigned int u0 = P[(size_t)j0 * 32 + lane];
            unsigned int u1 = P[(size_t)j1 * 32 + lane];
            unsigned int u2 = P[(size_t)j2 * 32 + lane];
            unsigned int u3 = P[(size_t)j3 * 32 + lane];
            unsigned int u4 = P[(size_t)j4 * 32 + lane];
            unsigned int u5 = P[(size_t)j5 * 32 + lane];
            unsigned int u6 = P[(size_t)j6 * 32 + lane];
            unsigned int u7 = P[(size_t)j7 * 32 + lane];
            ax += bflo(u0) +
                  ((1 < rem) ? bflo(u1) : 0.f) + ((2 < rem) ? bflo(u2) : 0.f) +
                  ((3 < rem) ? bflo(u3) : 0.f) + ((4 < rem) ? bflo(u4) : 0.f) +
                  ((5 < rem) ? bflo(u5) : 0.f) + ((6 < rem) ? bflo(u6) : 0.f) +
                  ((7 < rem) ? bflo(u7) : 0.f);
            ay += bfhi(u0) +
                  ((1 < rem) ? bfhi(u1) : 0.f) + ((2 < rem) ? bfhi(u2) : 0.f) +
                  ((3 < rem) ? bfhi(u3) : 0.f) + ((4 < rem) ? bfhi(u4) : 0.f) +
                  ((5 < rem) ? bfhi(u5) : 0.f) + ((6 < rem) ? bfhi(u6) : 0.f) +
                  ((7 < rem) ? bfhi(u7) : 0.f);
        }
    } else {
        // fallback (statistically never: span ~ Poisson(264), cap 768)
        for (int idx = s; idx < e; ++idx) {
            unsigned int u = P[(size_t)col[idx] * 32 + lane];
            ax += bflo(u);
            ay += bfhi(u);
        }
    }

    float dv = dinv[node];
    float2 bb = ((const float2*)bias)[plane * 32 + lane];
    float2 o;
    o.x = fmaxf(fmaf(dv, ax, bb.x), 0.f);
    o.y = fmaxf(fmaf(dv, ay, bb.y), 0.f);
    ((float2*)out)[(size_t)node * 64 + plane * 32 + lane] = o;
}

// ----------------------------------------------------------------
extern "C" void kernel_launch(void* const* d_in, const int* in_sizes, int n_in,
                              void* d_out, int out_size, void* d_ws, size_t ws_size,
                              hipStream_t stream) {
    const float* x    = (const float*)d_in[0];
    const int*   edge = (const int*)d_in[1];
    const float* W0   = (const float*)d_in[2];
    const float* b0   = (const float*)d_in[3];
    const float* W1   = (const float*)d_in[4];
    const float* b1   = (const float*)d_in[5];
    float* out = (float*)d_out;

    const int N_ = in_sizes[0] / D;
    const int E_ = in_sizes[1] / 2;
    const int* srcp = edge;       // edge_index[0]
    const int* dstp = edge + E_;  // edge_index[1]

    const int NB   = (E_ + CHUNK - 1) / CHUNK;
    const int NBUK = (N_ + 255) >> 8;

    char* p = (char*)d_ws;
    auto carve = [&](size_t bytes) { char* q = p; p += (bytes + 255) & ~(size_t)255; return q; };
    int*          blockhist = (int*)          carve((size_t)NB * 256 * 4);
    int*          buck_offs = (int*)          carve((size_t)(NBUK + 1) * 4);
    int*          offs      = (int*)          carve((size_t)(N_ + 1) * 4);
    float*        dinv      = (float*)        carve((size_t)N_ * 4);
    unsigned int* buf       = (unsigned int*) carve((size_t)E_ * 4);
    int*          col       = (int*)          carve((size_t)E_ * 4);
    unsigned int* gu        = (unsigned int*) carve((size_t)N_ * 64 * 4); // 2 planes x N x 32 uints
    short8*       whi0      = (short8*)       carve(2048 * 16);
    short8*       wlo0      = (short8*)       carve(2048 * 16);
    short8*       whi1      = (short8*)       carve(2048 * 16);
    short8*       wlo1      = (short8*)       carve(2048 * 16);

    k01_swz_hist    <<<16 + NB, 256, 0, stream>>>(W0, W1, whi0, wlo0, whi1, wlo1,
                                                  dstp, blockhist, E_);
    k23_scan_scatter<<<NB,      256, 0, stream>>>(blockhist, dstp, srcp, buck_offs, buf,
                                                  NB, NBUK, E_);
    k4_bucket       <<<NBUK,    256, 0, stream>>>(buf, buck_offs, offs, dinv, col, N_, E_);

    const int gmb = (N_ + 63) / 64;
    const int ngroups = (N_ + 7) / 8;               // 8 nodes (half-waves) per block
    const int agrid   = ((ngroups + 3) / 4) * 8;    // XCD-pinned flat grid (2 planes)

    gemm_mfma       <<<gmb,   256, 0, stream>>>(x, whi0, wlo0, dinv, gu, N_);
    aggregate_kernel<<<agrid, 256, 0, stream>>>(gu, offs, col, dinv, b0, out, N_, ngroups);
    gemm_mfma       <<<gmb,   256, 0, stream>>>(out, whi1, wlo1, dinv, gu, N_);
    aggregate_kernel<<<agrid, 256, 0, stream>>>(gu, offs, col, dinv, b1, out, N_, ngroups);
}